// Round 14
// baseline (237.942 us; speedup 1.0000x reference)
//
#include <hip/hip_runtime.h>
#include <math.h>

#define N_NODES 100000
#define N_EDGES 1600000
#define HID 64
#define N_LAYERS 3
#define N_GRAPHS 500

#define BUK_SHIFT 9
#define BUK_NODES 512                                   // 1 << BUK_SHIFT
#define NBUK ((N_NODES + BUK_NODES - 1) / BUK_NODES)    // 196
#define BIN_BLOCKS 256
#define CHUNK ((N_EDGES + BIN_BLOCKS - 1) / BIN_BLOCKS) // 6250
#define BCAP 16384   // bin slots per bucket (mean 8163, sigma ~90 -> safe)
#define PCAP 20480   // padded psrc slots per bucket

typedef _Float16 half_t;
typedef __attribute__((ext_vector_type(8))) _Float16 f16x8;
typedef __attribute__((ext_vector_type(4))) float f32x4;

__device__ __forceinline__ float elu_f(float x) { return x > 0.f ? x : expm1f(x); }
__device__ __forceinline__ int pad8(int c) { return (c + 7) & ~7; }

// ---- CSR build: fixed-capacity bucket-strided, 2 kernels ----

__global__ void kA_bin(const int* __restrict__ ei, int* __restrict__ bcur,
                       unsigned int* __restrict__ bin) {
    __shared__ int h[NBUK];
    __shared__ int rsv[NBUK];
    for (int i = threadIdx.x; i < NBUK; i += 256) h[i] = 0;
    __syncthreads();
    int lo = blockIdx.x * CHUNK;
    int hi = min(lo + CHUNK, N_EDGES);
    for (int e = lo + (int)threadIdx.x; e < hi; e += 256)
        atomicAdd(&h[ei[N_EDGES + e] >> BUK_SHIFT], 1);
    __syncthreads();
    for (int i = threadIdx.x; i < NBUK; i += 256) {
        int c = h[i];
        rsv[i] = c ? atomicAdd(&bcur[i], c) : 0;
        h[i] = 0;   // reuse as local cursor
    }
    __syncthreads();
    for (int e = lo + (int)threadIdx.x; e < hi; e += 256) {
        int d = ei[N_EDGES + e];
        int s = ei[e];
        int b = d >> BUK_SHIFT;
        int pos = rsv[b] + atomicAdd(&h[b], 1);
        if (pos < BCAP)
            bin[(size_t)b * BCAP + pos] = (unsigned)s | ((unsigned)(d & (BUK_NODES - 1)) << 17);
    }
}

// one block per bucket: LDS count -> padded LDS scan -> poff/plen/dis -> psrc
// (pads -> dummy zero row N_NODES). Block 0 zeroes Ba[N]/Bb[N]; blocks 0..47
// also build the fp16 transposed weight table W16T[l][col][k].
__global__ void kB_build(const unsigned int* __restrict__ bin,
                         const int* __restrict__ bcur,
                         int* __restrict__ poff, int* __restrict__ plen,
                         float* __restrict__ dis, int* __restrict__ psrc,
                         half_t* __restrict__ Ba, half_t* __restrict__ Bb,
                         const float* __restrict__ Ws, half_t* __restrict__ W16T) {
    __shared__ int cnt[BUK_NODES];
    __shared__ int excl[BUK_NODES];
    __shared__ int ps[256];
    int b = blockIdx.x;
    int t = threadIdx.x;
    int ecnt = min(bcur[b], BCAP);
    size_t e0 = (size_t)b * BCAP;
    size_t p0 = (size_t)b * PCAP;
    int n0 = b << BUK_SHIFT;

    if (b == 0 && t < HID) {
        Ba[(size_t)N_NODES * HID + t] = (half_t)0.f;
        Bb[(size_t)N_NODES * HID + t] = (half_t)0.f;
    }
    if (b < 48) {   // W16T: 3*64*64 = 12288 elements, 256 per block
        int i = b * 256 + t;
        int l = i >> 12, k = (i >> 6) & 63, c = i & 63;
        W16T[(size_t)l * 4096 + c * 64 + k] = (half_t)Ws[(size_t)l * 4096 + k * 64 + c];
    }

    cnt[t] = 0; cnt[t + 256] = 0;
    __syncthreads();
    for (int e = t; e < ecnt; e += 256)
        atomicAdd(&cnt[bin[e0 + e] >> 17], 1);
    __syncthreads();
    int pc0 = pad8(cnt[2 * t]), pc1 = pad8(cnt[2 * t + 1]);
    int psum = pc0 + pc1;
    ps[t] = psum;
    __syncthreads();
    for (int o = 1; o < 256; o <<= 1) {
        int u = (t >= o) ? ps[t - o] : 0;
        __syncthreads();
        ps[t] += u;
        __syncthreads();
    }
    int pexcl = ps[t] - psum;
    excl[2 * t] = pexcl;
    excl[2 * t + 1] = pexcl + pc0;
    int ptot = ps[255];
    __syncthreads();
    for (int i = t; i < BUK_NODES; i += 256) {
        int n = n0 + i;
        if (n < N_NODES) {
            poff[n] = (int)p0 + excl[i];
            plen[n] = pad8(cnt[i]);
            dis[n] = rsqrtf((float)cnt[i] + 1.0f);   // +1 self loop
        }
    }
    for (int j = t; j < ptot; j += 256) psrc[p0 + j] = N_NODES;
    __syncthreads();
    cnt[t] = excl[t]; cnt[t + 256] = excl[t + 256];  // cnt becomes cursor
    __syncthreads();
    for (int e = t; e < ecnt; e += 256) {
        unsigned v = bin[e0 + e];
        int dloc = v >> 17;
        int pos = atomicAdd(&cnt[dloc], 1);
        if (pos < PCAP) psrc[p0 + pos] = (int)(v & 0x1FFFFu);
    }
}

// ---- shared device helpers ----

// branch-free padded gather-sum of one node's in-edge messages (lane = feature)
__device__ __forceinline__ float gather_row(const int* __restrict__ psrc,
                                            const half_t* __restrict__ B,
                                            int p, int p1, int lane, float acc) {
    for (; p + 16 <= p1; p += 16) {
        int s[16];
#pragma unroll
        for (int i = 0; i < 16; i++) s[i] = psrc[p + i];
        float v[16];
#pragma unroll
        for (int i = 0; i < 16; i++) v[i] = (float)B[(size_t)s[i] * HID + lane];
        acc += (((v[0] + v[1]) + (v[2] + v[3])) + ((v[4] + v[5]) + (v[6] + v[7])))
             + (((v[8] + v[9]) + (v[10] + v[11])) + ((v[12] + v[13]) + (v[14] + v[15])));
    }
    if (p < p1) {   // exactly one 8-block remains (padded length % 8 == 0)
        int s[8];
#pragma unroll
        for (int i = 0; i < 8; i++) s[i] = psrc[p + i];
        float v[8];
#pragma unroll
        for (int i = 0; i < 8; i++) v[i] = (float)B[(size_t)s[i] * HID + lane];
        acc += ((v[0] + v[1]) + (v[2] + v[3])) + ((v[4] + v[5]) + (v[6] + v[7]));
    }
    return acc;
}

// 8 MFMAs: rows from A-fragments a0/a1, W16T slab wt -> writes B16 rows r0..r0+15
// Layouts (m89-verified family): A row=lane&15, k=(lane>>4)*8+j; D col=lane&15,
// row=(lane>>4)*4+reg.
__device__ __forceinline__ void mfma_rows(f16x8 a0, f16x8 a1,
                                          const half_t* __restrict__ wt, int lane,
                                          const float* __restrict__ dis, int r0,
                                          half_t* __restrict__ Bout) {
    int goff = (lane >> 4) * 8;
    int wcol = (lane & 15) * HID + goff;
    f32x4 c0 = {0.f, 0.f, 0.f, 0.f}, c1 = c0, c2 = c0, c3 = c0;
    {
        f16x8 b0 = *(const f16x8*)&wt[wcol];
        f16x8 b1 = *(const f16x8*)&wt[wcol + 32];
        c0 = __builtin_amdgcn_mfma_f32_16x16x32_f16(a0, b0, c0, 0, 0, 0);
        c0 = __builtin_amdgcn_mfma_f32_16x16x32_f16(a1, b1, c0, 0, 0, 0);
    }
    {
        f16x8 b0 = *(const f16x8*)&wt[1024 + wcol];
        f16x8 b1 = *(const f16x8*)&wt[1024 + wcol + 32];
        c1 = __builtin_amdgcn_mfma_f32_16x16x32_f16(a0, b0, c1, 0, 0, 0);
        c1 = __builtin_amdgcn_mfma_f32_16x16x32_f16(a1, b1, c1, 0, 0, 0);
    }
    {
        f16x8 b0 = *(const f16x8*)&wt[2048 + wcol];
        f16x8 b1 = *(const f16x8*)&wt[2048 + wcol + 32];
        c2 = __builtin_amdgcn_mfma_f32_16x16x32_f16(a0, b0, c2, 0, 0, 0);
        c2 = __builtin_amdgcn_mfma_f32_16x16x32_f16(a1, b1, c2, 0, 0, 0);
    }
    {
        f16x8 b0 = *(const f16x8*)&wt[3072 + wcol];
        f16x8 b1 = *(const f16x8*)&wt[3072 + wcol + 32];
        c3 = __builtin_amdgcn_mfma_f32_16x16x32_f16(a0, b0, c3, 0, 0, 0);
        c3 = __builtin_amdgcn_mfma_f32_16x16x32_f16(a1, b1, c3, 0, 0, 0);
    }
    int rg = (lane >> 4) * 4;
    int col = lane & 15;
#pragma unroll
    for (int r = 0; r < 4; r++) {
        int row = r0 + rg + r;
        float dv = dis[row];
        size_t rb = (size_t)row * HID;
        Bout[rb + col]      = (half_t)(c0[r] * dv);
        Bout[rb + 16 + col] = (half_t)(c1[r] * dv);
        Bout[rb + 32 + col] = (half_t)(c2[r] * dv);
        Bout[rb + 48 + col] = (half_t)(c3[r] * dv);
    }
}

// ---- layer kernels ----

// Layer-0 GEMM: one wave = 16 rows x 64 cols from fp32 x, MFMA, no LDS.
__global__ void k_gemm0(const float* __restrict__ X, const half_t* __restrict__ wt,
                        const float* __restrict__ dis, half_t* __restrict__ Bout, int n) {
    int lane = threadIdx.x & 63;
    int wid = (blockIdx.x * blockDim.x + threadIdx.x) >> 6;
    int r0 = wid << 4;
    if (r0 >= n) return;
    size_t rowbase = (size_t)(r0 + (lane & 15)) * HID;
    int goff = (lane >> 4) * 8;
    f16x8 a0, a1;
#pragma unroll
    for (int j = 0; j < 8; j++) a0[j] = (half_t)X[rowbase + goff + j];
#pragma unroll
    for (int j = 0; j < 8; j++) a1[j] = (half_t)X[rowbase + 32 + goff + j];
    mfma_rows(a0, a1, wt, lane, dis, r0, Bout);
}

// Fused agg(l) + gemm(l+1): one wave = 16 consecutive nodes.
// Per node: gather-sum (lane=feature) -> *dis -> elu(+bias) -> LDS tile;
// then transpose via ds_read into A-fragments and MFMA with wt. No A16 trip.
__global__ void k_agg_gemm(const int* __restrict__ poff, const int* __restrict__ plen,
                           const int* __restrict__ psrc, const float* __restrict__ dis,
                           const half_t* __restrict__ Bin, const half_t* __restrict__ wt,
                           const float* __restrict__ bias,
                           half_t* __restrict__ Bout, int n) {
    __shared__ half_t tile[4][16 * 72];      // per-wave 16x64 tile, stride 72 (bank-safe)
    int lane = threadIdx.x & 63;
    int wv = threadIdx.x >> 6;
    int wid = (blockIdx.x * blockDim.x + threadIdx.x) >> 6;
    int r0 = wid << 4;                       // N % 16 == 0
    if (r0 >= n) return;
    half_t* tl = tile[wv];
    float bl = bias[lane];

    for (int j = 0; j < 16; j++) {
        int node = r0 + j;
        float acc = (float)Bin[(size_t)node * HID + lane];
        int p = poff[node];
        acc = gather_row(psrc, Bin, p, p + plen[node], lane, acc);
        tl[j * 72 + lane] = (half_t)elu_f(acc * dis[node] + bl);
    }
    asm volatile("s_waitcnt lgkmcnt(0)" ::: "memory");
    __builtin_amdgcn_sched_barrier(0);

    int goff = (lane >> 4) * 8;
    f16x8 a0 = *(const f16x8*)&tl[(lane & 15) * 72 + goff];
    f16x8 a1 = *(const f16x8*)&tl[(lane & 15) * 72 + 32 + goff];
    mfma_rows(a0, a1, wt, lane, dis, r0, Bout);
}

// Final-layer agg: one wave per dst node -> A16 (for pooling).
__global__ void k_agg(const int* __restrict__ poff, const int* __restrict__ plen,
                      const int* __restrict__ psrc,
                      const float* __restrict__ dis, const half_t* __restrict__ Bin,
                      half_t* __restrict__ A16, int n) {
    int lane = threadIdx.x & 63;
    int node = __builtin_amdgcn_readfirstlane((blockIdx.x * blockDim.x + threadIdx.x) >> 6);
    if (node >= n) return;
    float acc = (float)Bin[(size_t)node * HID + lane];
    int p = poff[node];
    acc = gather_row(psrc, Bin, p, p + plen[node], lane, acc);
    A16[(size_t)node * HID + lane] = (half_t)(acc * dis[node]);
}

// One block per graph (batch sorted): binary-search range, register-accumulate
// masked elu(A16+bias), LDS cross-wave reduce, dot w, write out[g].
__global__ void k_pool_final(const half_t* __restrict__ A16, const float* __restrict__ bias,
                             const int* __restrict__ mask, const int* __restrict__ batch,
                             const float* __restrict__ w, const float* __restrict__ b,
                             float* __restrict__ out) {
    __shared__ float sacc[4][HID];
    __shared__ float scnt[4];
    int g = blockIdx.x;
    int t = threadIdx.x;
    int lane = t & 63;
    int wv = t >> 6;

    int lo = 0, hi = N_NODES;
    while (lo < hi) { int mid = (lo + hi) >> 1; if (batch[mid] < g) lo = mid + 1; else hi = mid; }
    int n0 = lo;
    hi = N_NODES;
    while (lo < hi) { int mid = (lo + hi) >> 1; if (batch[mid] < g + 1) lo = mid + 1; else hi = mid; }
    int n1 = lo;

    float bl = bias[lane];
    float acc0 = 0.f, acc1 = 0.f;
    float cnt0 = 0.f, cnt1 = 0.f;
    int n = n0 + wv;
    for (; n + 4 < n1; n += 8) {
        int m0 = mask[n], m1 = mask[n + 4];
        float v0 = (float)A16[(size_t)n * HID + lane];
        float v1 = (float)A16[(size_t)(n + 4) * HID + lane];
        if (m0) { acc0 += elu_f(v0 + bl); cnt0 += 1.f; }
        if (m1) { acc1 += elu_f(v1 + bl); cnt1 += 1.f; }
    }
    if (n < n1 && mask[n]) { acc0 += elu_f((float)A16[(size_t)n * HID + lane] + bl); cnt0 += 1.f; }
    acc0 += acc1; cnt0 += cnt1;

    sacc[wv][lane] = acc0;
    if (lane == 0) scnt[wv] = cnt0;
    __syncthreads();
    if (wv == 0) {
        float v = sacc[0][lane] + sacc[1][lane] + sacc[2][lane] + sacc[3][lane];
        float c = scnt[0] + scnt[1] + scnt[2] + scnt[3];
        v = v / fmaxf(c, 1.0f) * w[lane];
#pragma unroll
        for (int o = 32; o > 0; o >>= 1) v += __shfl_down(v, o);
        if (lane == 0) out[g] = v + b[0];
    }
}

extern "C" void kernel_launch(void* const* d_in, const int* in_sizes, int n_in,
                              void* d_out, int out_size, void* d_ws, size_t ws_size,
                              hipStream_t stream) {
    const float* x     = (const float*)d_in[0];
    const int*   ei    = (const int*)d_in[1];   // [2, E]: src = ei[e], dst = ei[E+e]
    const int*   mask  = (const int*)d_in[2];
    const int*   batch = (const int*)d_in[3];
    const float* Ws    = (const float*)d_in[4]; // [3, 64, 64]
    const float* bs    = (const float*)d_in[5]; // [3, 64]
    const float* lw    = (const float*)d_in[6]; // [64]
    const float* lb    = (const float*)d_in[7]; // [1]
    float* out = (float*)d_out;

    half_t* A16  = (half_t*)d_ws;                              // N*64 f16
    half_t* Ba   = A16 + (size_t)N_NODES * HID;                // (N+1)*64 f16
    half_t* Bb   = Ba + (size_t)(N_NODES + 1) * HID;           // (N+1)*64 f16
    float*  dis  = (float*)(Bb + (size_t)(N_NODES + 1) * HID); // N
    int*    poff = (int*)(dis + N_NODES);                      // N
    int*    plen = poff + N_NODES;                             // N
    int*    bcur = plen + N_NODES;                             // NBUK (pad to 200)
    half_t* W16T = (half_t*)(bcur + 200);                      // 3*64*64 f16
    int*    psrc = (int*)(W16T + (size_t)N_LAYERS * HID * HID);// NBUK*PCAP
    unsigned int* bin = (unsigned int*)(psrc + (size_t)NBUK * PCAP); // NBUK*BCAP

    hipMemsetAsync(bcur, 0, NBUK * sizeof(int), stream);

    // ---- CSR build (+ weight table + dummy rows) ----
    kA_bin<<<BIN_BLOCKS, 256, 0, stream>>>(ei, bcur, bin);
    kB_build<<<NBUK, 256, 0, stream>>>(bin, bcur, poff, plen, dis, psrc,
                                       Ba, Bb, Ws, W16T);

    // ---- layers: gemm0 -> [agg0+gemm1] -> [agg1+gemm2] -> agg2 -> pool ----
    const int wave_blocks = (N_NODES / 16 + 3) / 4;   // 1 wave = 16 rows
    const int row_blocks  = (N_NODES + 3) / 4;        // k_agg: 1 node/wave

    k_gemm0<<<wave_blocks, 256, 0, stream>>>(x, W16T, dis, Ba, N_NODES);
    k_agg_gemm<<<wave_blocks, 256, 0, stream>>>(poff, plen, psrc, dis, Ba,
                                                W16T + 4096, bs, Bb, N_NODES);
    k_agg_gemm<<<wave_blocks, 256, 0, stream>>>(poff, plen, psrc, dis, Bb,
                                                W16T + 8192, bs + HID, Ba, N_NODES);
    k_agg<<<row_blocks, 256, 0, stream>>>(poff, plen, psrc, dis, Ba, A16, N_NODES);

    k_pool_final<<<N_GRAPHS, 256, 0, stream>>>(A16, bs + 2 * HID, mask, batch, lw, lb, out);
}

// Round 15
// 231.953 us; speedup vs baseline: 1.0258x; 1.0258x over previous
//
#include <hip/hip_runtime.h>
#include <math.h>

#define N_NODES 100000
#define N_EDGES 1600000
#define HID 64
#define N_LAYERS 3
#define N_GRAPHS 500

#define BUK_SHIFT 9
#define BUK_NODES 512                                   // 1 << BUK_SHIFT
#define NBUK ((N_NODES + BUK_NODES - 1) / BUK_NODES)    // 196
#define BIN_BLOCKS 256
#define CHUNK ((N_EDGES + BIN_BLOCKS - 1) / BIN_BLOCKS) // 6250
#define BCAP 16384   // bin slots per bucket (mean 8163, sigma ~90 -> safe)
#define PCAP 20480   // padded psrc slots per bucket

typedef _Float16 half_t;
typedef __attribute__((ext_vector_type(8))) _Float16 f16x8;
typedef __attribute__((ext_vector_type(4))) float f32x4;

__device__ __forceinline__ float elu_f(float x) { return x > 0.f ? x : expm1f(x); }
__device__ __forceinline__ int pad8(int c) { return (c + 7) & ~7; }

// ---- CSR build: fixed-capacity bucket-strided, 2 kernels ----

__global__ void kA_bin(const int* __restrict__ ei, int* __restrict__ bcur,
                       unsigned int* __restrict__ bin) {
    __shared__ int h[NBUK];
    __shared__ int rsv[NBUK];
    for (int i = threadIdx.x; i < NBUK; i += 256) h[i] = 0;
    __syncthreads();
    int lo = blockIdx.x * CHUNK;
    int hi = min(lo + CHUNK, N_EDGES);
    for (int e = lo + (int)threadIdx.x; e < hi; e += 256)
        atomicAdd(&h[ei[N_EDGES + e] >> BUK_SHIFT], 1);
    __syncthreads();
    for (int i = threadIdx.x; i < NBUK; i += 256) {
        int c = h[i];
        rsv[i] = c ? atomicAdd(&bcur[i], c) : 0;
        h[i] = 0;   // reuse as local cursor
    }
    __syncthreads();
    for (int e = lo + (int)threadIdx.x; e < hi; e += 256) {
        int d = ei[N_EDGES + e];
        int s = ei[e];
        int b = d >> BUK_SHIFT;
        int pos = rsv[b] + atomicAdd(&h[b], 1);
        if (pos < BCAP)
            bin[(size_t)b * BCAP + pos] = (unsigned)s | ((unsigned)(d & (BUK_NODES - 1)) << 17);
    }
}

// one block per bucket: LDS count -> padded LDS scan -> poff/plen/dis -> psrc
// (pads -> dummy zero row N_NODES). Block 0 zeroes B16[N]; blocks 0..47 also
// build the fp16 transposed weight table W16T[l][col][k].
__global__ void kB_build(const unsigned int* __restrict__ bin,
                         const int* __restrict__ bcur,
                         int* __restrict__ poff, int* __restrict__ plen,
                         float* __restrict__ dis, int* __restrict__ psrc,
                         half_t* __restrict__ B16,
                         const float* __restrict__ Ws, half_t* __restrict__ W16T) {
    __shared__ int cnt[BUK_NODES];
    __shared__ int excl[BUK_NODES];
    __shared__ int ps[256];
    int b = blockIdx.x;
    int t = threadIdx.x;
    int ecnt = min(bcur[b], BCAP);
    size_t e0 = (size_t)b * BCAP;
    size_t p0 = (size_t)b * PCAP;
    int n0 = b << BUK_SHIFT;

    if (b == 0 && t < HID) B16[(size_t)N_NODES * HID + t] = (half_t)0.f;
    if (b < 48) {   // W16T: 3*64*64 = 12288 elements, 256 per block
        int i = b * 256 + t;
        int l = i >> 12, k = (i >> 6) & 63, c = i & 63;
        W16T[(size_t)l * 4096 + c * 64 + k] = (half_t)Ws[(size_t)l * 4096 + k * 64 + c];
    }

    cnt[t] = 0; cnt[t + 256] = 0;
    __syncthreads();
    for (int e = t; e < ecnt; e += 256)
        atomicAdd(&cnt[bin[e0 + e] >> 17], 1);
    __syncthreads();
    int pc0 = pad8(cnt[2 * t]), pc1 = pad8(cnt[2 * t + 1]);
    int psum = pc0 + pc1;
    ps[t] = psum;
    __syncthreads();
    for (int o = 1; o < 256; o <<= 1) {
        int u = (t >= o) ? ps[t - o] : 0;
        __syncthreads();
        ps[t] += u;
        __syncthreads();
    }
    int pexcl = ps[t] - psum;
    excl[2 * t] = pexcl;
    excl[2 * t + 1] = pexcl + pc0;
    int ptot = ps[255];
    __syncthreads();
    for (int i = t; i < BUK_NODES; i += 256) {
        int n = n0 + i;
        if (n < N_NODES) {
            poff[n] = (int)p0 + excl[i];
            plen[n] = pad8(cnt[i]);
            dis[n] = rsqrtf((float)cnt[i] + 1.0f);   // +1 self loop
        }
    }
    for (int j = t; j < ptot; j += 256) psrc[p0 + j] = N_NODES;
    __syncthreads();
    cnt[t] = excl[t]; cnt[t + 256] = excl[t + 256];  // cnt becomes cursor
    __syncthreads();
    for (int e = t; e < ecnt; e += 256) {
        unsigned v = bin[e0 + e];
        int dloc = v >> 17;
        int pos = atomicAdd(&cnt[dloc], 1);
        if (pos < PCAP) psrc[p0 + pos] = (int)(v & 0x1FFFFu);
    }
}

// ---- MFMA GEMM: one wave = 16 rows x 64 cols, no LDS. ----
// Fragment layouts (m89-verified family):
//   A: row = lane&15, k = (lane>>4)*8 + j   (f16x8, b128 load)
//   B: col = lane&15, k = (lane>>4)*8 + j   (from W16T[col][k])
//   D: col = lane&15, row = (lane>>4)*4 + reg
__device__ __forceinline__ f16x8 make_afrag(const float* Xf, const half_t* Xh,
                                            const float* bias, int act,
                                            size_t rowbase, int k) {
    f16x8 a;
    if (act) {
        f16x8 xu = *(const f16x8*)(Xh + rowbase + k);
        float4 ba = *(const float4*)(bias + k);
        float4 bb = *(const float4*)(bias + k + 4);
        a[0] = (half_t)elu_f((float)xu[0] + ba.x);
        a[1] = (half_t)elu_f((float)xu[1] + ba.y);
        a[2] = (half_t)elu_f((float)xu[2] + ba.z);
        a[3] = (half_t)elu_f((float)xu[3] + ba.w);
        a[4] = (half_t)elu_f((float)xu[4] + bb.x);
        a[5] = (half_t)elu_f((float)xu[5] + bb.y);
        a[6] = (half_t)elu_f((float)xu[6] + bb.z);
        a[7] = (half_t)elu_f((float)xu[7] + bb.w);
    } else {
        float4 xa = *(const float4*)(Xf + rowbase + k);
        float4 xb = *(const float4*)(Xf + rowbase + k + 4);
        a[0] = (half_t)xa.x; a[1] = (half_t)xa.y;
        a[2] = (half_t)xa.z; a[3] = (half_t)xa.w;
        a[4] = (half_t)xb.x; a[5] = (half_t)xb.y;
        a[6] = (half_t)xb.z; a[7] = (half_t)xb.w;
    }
    return a;
}

__global__ void k_gemm(const float* __restrict__ Xf, const half_t* __restrict__ Xh,
                       const half_t* __restrict__ wt, const float* __restrict__ bias,
                       int act, const float* __restrict__ dis,
                       half_t* __restrict__ B16, int n) {
    int lane = threadIdx.x & 63;
    int wid = (blockIdx.x * blockDim.x + threadIdx.x) >> 6;
    int r0 = wid << 4;                       // 16 rows per wave; N % 16 == 0
    if (r0 >= n) return;
    size_t rowbase = (size_t)(r0 + (lane & 15)) * HID;
    int goff = (lane >> 4) * 8;

    f16x8 a0 = make_afrag(Xf, Xh, bias, act, rowbase, goff);
    f16x8 a1 = make_afrag(Xf, Xh, bias, act, rowbase, 32 + goff);

    int wcol = (lane & 15) * HID + goff;     // W16T[col][k] base for this lane
    f32x4 c0 = {0.f, 0.f, 0.f, 0.f}, c1 = c0, c2 = c0, c3 = c0;
    {
        f16x8 b0 = *(const f16x8*)&wt[wcol];
        f16x8 b1 = *(const f16x8*)&wt[wcol + 32];
        c0 = __builtin_amdgcn_mfma_f32_16x16x32_f16(a0, b0, c0, 0, 0, 0);
        c0 = __builtin_amdgcn_mfma_f32_16x16x32_f16(a1, b1, c0, 0, 0, 0);
    }
    {
        f16x8 b0 = *(const f16x8*)&wt[1024 + wcol];
        f16x8 b1 = *(const f16x8*)&wt[1024 + wcol + 32];
        c1 = __builtin_amdgcn_mfma_f32_16x16x32_f16(a0, b0, c1, 0, 0, 0);
        c1 = __builtin_amdgcn_mfma_f32_16x16x32_f16(a1, b1, c1, 0, 0, 0);
    }
    {
        f16x8 b0 = *(const f16x8*)&wt[2048 + wcol];
        f16x8 b1 = *(const f16x8*)&wt[2048 + wcol + 32];
        c2 = __builtin_amdgcn_mfma_f32_16x16x32_f16(a0, b0, c2, 0, 0, 0);
        c2 = __builtin_amdgcn_mfma_f32_16x16x32_f16(a1, b1, c2, 0, 0, 0);
    }
    {
        f16x8 b0 = *(const f16x8*)&wt[3072 + wcol];
        f16x8 b1 = *(const f16x8*)&wt[3072 + wcol + 32];
        c3 = __builtin_amdgcn_mfma_f32_16x16x32_f16(a0, b0, c3, 0, 0, 0);
        c3 = __builtin_amdgcn_mfma_f32_16x16x32_f16(a1, b1, c3, 0, 0, 0);
    }

    int rg = (lane >> 4) * 4;
    int col = lane & 15;
#pragma unroll
    for (int r = 0; r < 4; r++) {
        int row = r0 + rg + r;
        float dv = dis[row];
        size_t rb = (size_t)row * HID;
        B16[rb + col]      = (half_t)(c0[r] * dv);
        B16[rb + 16 + col] = (half_t)(c1[r] * dv);
        B16[rb + 32 + col] = (half_t)(c2[r] * dv);
        B16[rb + 48 + col] = (half_t)(c3[r] * dv);
    }
}

// One wave per dst node, padded CSR (plen multiple of 8, pads -> zero row
// B16[N]): branch-free 16-deep fp16 gather, fp32 accumulate, fp16 store.
// One node per wave preserves ~100k waves of TLP (round-14 lesson: fusing 16
// nodes/wave collapsed latency hiding and regressed).
__global__ void k_agg(const int* __restrict__ poff, const int* __restrict__ plen,
                      const int* __restrict__ psrc,
                      const float* __restrict__ dis, const half_t* __restrict__ B16,
                      half_t* __restrict__ A16, int n) {
    int lane = threadIdx.x & 63;
    int node = __builtin_amdgcn_readfirstlane((blockIdx.x * blockDim.x + threadIdx.x) >> 6);
    if (node >= n) return;
    float acc = (float)B16[(size_t)node * HID + lane];
    int p = poff[node];
    int p1 = p + plen[node];
    for (; p + 16 <= p1; p += 16) {
        int s[16];
#pragma unroll
        for (int i = 0; i < 16; i++) s[i] = psrc[p + i];
        float v[16];
#pragma unroll
        for (int i = 0; i < 16; i++) v[i] = (float)B16[(size_t)s[i] * HID + lane];
        acc += (((v[0] + v[1]) + (v[2] + v[3])) + ((v[4] + v[5]) + (v[6] + v[7])))
             + (((v[8] + v[9]) + (v[10] + v[11])) + ((v[12] + v[13]) + (v[14] + v[15])));
    }
    if (p < p1) {
        int s[8];
#pragma unroll
        for (int i = 0; i < 8; i++) s[i] = psrc[p + i];
        float v[8];
#pragma unroll
        for (int i = 0; i < 8; i++) v[i] = (float)B16[(size_t)s[i] * HID + lane];
        acc += ((v[0] + v[1]) + (v[2] + v[3])) + ((v[4] + v[5]) + (v[6] + v[7]));
    }
    A16[(size_t)node * HID + lane] = (half_t)(acc * dis[node]);
}

// One block per graph (batch sorted): binary-search range, register-accumulate
// masked elu(A16+bias), LDS cross-wave reduce, dot w, write out[g].
__global__ void k_pool_final(const half_t* __restrict__ A16, const float* __restrict__ bias,
                             const int* __restrict__ mask, const int* __restrict__ batch,
                             const float* __restrict__ w, const float* __restrict__ b,
                             float* __restrict__ out) {
    __shared__ float sacc[4][HID];
    __shared__ float scnt[4];
    int g = blockIdx.x;
    int t = threadIdx.x;
    int lane = t & 63;
    int wv = t >> 6;

    int lo = 0, hi = N_NODES;
    while (lo < hi) { int mid = (lo + hi) >> 1; if (batch[mid] < g) lo = mid + 1; else hi = mid; }
    int n0 = lo;
    hi = N_NODES;
    while (lo < hi) { int mid = (lo + hi) >> 1; if (batch[mid] < g + 1) lo = mid + 1; else hi = mid; }
    int n1 = lo;

    float bl = bias[lane];
    float acc0 = 0.f, acc1 = 0.f;
    float cnt0 = 0.f, cnt1 = 0.f;
    int n = n0 + wv;
    for (; n + 4 < n1; n += 8) {
        int m0 = mask[n], m1 = mask[n + 4];
        float v0 = (float)A16[(size_t)n * HID + lane];
        float v1 = (float)A16[(size_t)(n + 4) * HID + lane];
        if (m0) { acc0 += elu_f(v0 + bl); cnt0 += 1.f; }
        if (m1) { acc1 += elu_f(v1 + bl); cnt1 += 1.f; }
    }
    if (n < n1 && mask[n]) { acc0 += elu_f((float)A16[(size_t)n * HID + lane] + bl); cnt0 += 1.f; }
    acc0 += acc1; cnt0 += cnt1;

    sacc[wv][lane] = acc0;
    if (lane == 0) scnt[wv] = cnt0;
    __syncthreads();
    if (wv == 0) {
        float v = sacc[0][lane] + sacc[1][lane] + sacc[2][lane] + sacc[3][lane];
        float c = scnt[0] + scnt[1] + scnt[2] + scnt[3];
        v = v / fmaxf(c, 1.0f) * w[lane];
#pragma unroll
        for (int o = 32; o > 0; o >>= 1) v += __shfl_down(v, o);
        if (lane == 0) out[g] = v + b[0];
    }
}

extern "C" void kernel_launch(void* const* d_in, const int* in_sizes, int n_in,
                              void* d_out, int out_size, void* d_ws, size_t ws_size,
                              hipStream_t stream) {
    const float* x     = (const float*)d_in[0];
    const int*   ei    = (const int*)d_in[1];   // [2, E]: src = ei[e], dst = ei[E+e]
    const int*   mask  = (const int*)d_in[2];
    const int*   batch = (const int*)d_in[3];
    const float* Ws    = (const float*)d_in[4]; // [3, 64, 64]
    const float* bs    = (const float*)d_in[5]; // [3, 64]
    const float* lw    = (const float*)d_in[6]; // [64]
    const float* lb    = (const float*)d_in[7]; // [1]
    float* out = (float*)d_out;

    half_t* A16  = (half_t*)d_ws;                              // N*64 f16
    half_t* B16  = A16 + (size_t)N_NODES * HID;                // (N+1)*64 f16
    float*  dis  = (float*)(B16 + (size_t)(N_NODES + 1) * HID);// N
    int*    poff = (int*)(dis + N_NODES);                      // N
    int*    plen = poff + N_NODES;                             // N
    int*    bcur = plen + N_NODES;                             // NBUK (pad to 200)
    half_t* W16T = (half_t*)(bcur + 200);                      // 3*64*64 f16
    int*    psrc = (int*)(W16T + (size_t)N_LAYERS * HID * HID);// NBUK*PCAP
    unsigned int* bin = (unsigned int*)(psrc + (size_t)NBUK * PCAP); // NBUK*BCAP

    hipMemsetAsync(bcur, 0, NBUK * sizeof(int), stream);

    // ---- CSR build (+ weight table + dummy row) ----
    kA_bin<<<BIN_BLOCKS, 256, 0, stream>>>(ei, bcur, bin);
    kB_build<<<NBUK, 256, 0, stream>>>(bin, bcur, poff, plen, dis, psrc,
                                       B16, Ws, W16T);

    // ---- layers ----
    const int gemm_blocks = (N_NODES / 16 + 3) / 4;   // 1 wave = 16 rows
    const int row_blocks  = (N_NODES + 3) / 4;        // k_agg: 1 node/wave
    for (int l = 0; l < N_LAYERS; l++) {
        const float* bias_in = (l == 0) ? bs : bs + (l - 1) * HID;
        k_gemm<<<gemm_blocks, 256, 0, stream>>>((l == 0) ? x : nullptr,
                                                (l == 0) ? nullptr : A16,
                                                W16T + (size_t)l * HID * HID,
                                                bias_in, (l == 0) ? 0 : 1,
                                                dis, B16, N_NODES);
        k_agg<<<row_blocks, 256, 0, stream>>>(poff, plen, psrc, dis, B16, A16, N_NODES);
    }

    k_pool_final<<<N_GRAPHS, 256, 0, stream>>>(A16, bs + 2 * HID, mask, batch, lw, lb, out);
}